// Round 4
// baseline (316.591 us; speedup 1.0000x reference)
//
#include <hip/hip_runtime.h>

// Problem constants (fixed by reference)
#define NV 4000
#define NH 512
#define NM 50
#define CAP 96
#define NHOPS 6
#define VS 25          // v-splits in kC
#define VCH 160        // NV / VS
#define CB 16          // c-chunk blocks in kC (32 cols per block, 8 per wave)
#define TGRID 128      // tail-kernel grid (<=256 CUs -> all co-resident)

// ---------------------------------------------------------------------------
// KA: b<4000: CSR build (float4 scan) + immediately h[r] = relu(row@W1 + b1).
//     b in [4000,4128): w2q = W2 @ q.  b >= 4128: out = bo2, zero s/hid/sync.
__global__ void kA_csr_h(const float* __restrict__ adj, const float* __restrict__ query,
                         const float* __restrict__ W1, const float* __restrict__ b1,
                         const float* __restrict__ W2, const float* __restrict__ bo2,
                         int* __restrict__ rcnt, int* __restrict__ cols, float* __restrict__ vals,
                         float* __restrict__ h, float* __restrict__ w2q,
                         float* __restrict__ zreg, float* __restrict__ out) {
    int b = blockIdx.x;
    if (b < NV) {
        __shared__ int cnt;
        __shared__ int cs[CAP];
        __shared__ float vsh[CAP];
        if (threadIdx.x == 0) cnt = 0;
        __syncthreads();
        const float4* row4 = (const float4*)(adj + (size_t)b * NV);
        for (int i = threadIdx.x; i < NV / 4; i += 256) {
            float4 a = row4[i];
            if (a.x != 0.f) { int k = atomicAdd(&cnt, 1); if (k < CAP) { cs[k] = 4*i;   vsh[k] = a.x; } }
            if (a.y != 0.f) { int k = atomicAdd(&cnt, 1); if (k < CAP) { cs[k] = 4*i+1; vsh[k] = a.y; } }
            if (a.z != 0.f) { int k = atomicAdd(&cnt, 1); if (k < CAP) { cs[k] = 4*i+2; vsh[k] = a.z; } }
            if (a.w != 0.f) { int k = atomicAdd(&cnt, 1); if (k < CAP) { cs[k] = 4*i+3; vsh[k] = a.w; } }
        }
        __syncthreads();
        int n = cnt < CAP ? cnt : CAP;
        if (threadIdx.x == 0) rcnt[b] = n;
        if (threadIdx.x < n) {
            cols[b * CAP + threadIdx.x] = cs[threadIdx.x];
            vals[b * CAP + threadIdx.x] = vsh[threadIdx.x];
        }
        int c = threadIdx.x * 2;
        float2 acc = *(const float2*)(b1 + c);
        int j = 0;
        for (; j + 2 <= n; j += 2) {
            int c0 = cs[j], c1 = cs[j + 1];
            float v0 = vsh[j], v1 = vsh[j + 1];
            float2 wa = *(const float2*)(W1 + (size_t)c0 * NH + c);
            float2 wb = *(const float2*)(W1 + (size_t)c1 * NH + c);
            acc.x = fmaf(v0, wa.x, acc.x); acc.y = fmaf(v0, wa.y, acc.y);
            acc.x = fmaf(v1, wb.x, acc.x); acc.y = fmaf(v1, wb.y, acc.y);
        }
        if (j < n) {
            float2 wa = *(const float2*)(W1 + (size_t)cs[j] * NH + c);
            acc.x = fmaf(vsh[j], wa.x, acc.x); acc.y = fmaf(vsh[j], wa.y, acc.y);
        }
        float2 o = {fmaxf(acc.x, 0.f), fmaxf(acc.y, 0.f)};
        *(float2*)(h + (size_t)b * NH + c) = o;
    } else if (b < NV + 128) {
        __shared__ float qs[NH];
        qs[threadIdx.x] = query[threadIdx.x];
        qs[threadIdx.x + 256] = query[threadIdx.x + 256];
        __syncthreads();
        int wid = threadIdx.x >> 6, lane = threadIdx.x & 63;
        int k = (b - NV) * 4 + wid;
        const float* wr = W2 + (size_t)k * NH;
        float p = 0.f;
        for (int j = lane; j < NH; j += 64) p = fmaf(wr[j], qs[j], p);
        for (int o = 32; o > 0; o >>= 1) p += __shfl_down(p, o);
        if (lane == 0) w2q[k] = p;
    } else {
        int t = (b - NV - 128) * 256 + threadIdx.x;   // 0..4095
        if (t < NV) out[t] = bo2[t];
        if (t < 1152) zreg[t] = 0.f;                  // s[64] + hid[1024] + sync[64]
    }
}

// ---------------------------------------------------------------------------
// KB: g = spmm(adj, h); fused logits[r] = dot(g[r,:], w2q)  (unroll-2 gather)
__global__ void kB_spmm_g(const int* __restrict__ rcnt, const int* __restrict__ cols,
                          const float* __restrict__ vals, const float* __restrict__ h,
                          const float* __restrict__ w2q, float* __restrict__ g,
                          float* __restrict__ logits) {
    int r = blockIdx.x;
    __shared__ int cs[CAP];
    __shared__ float vsh[CAP];
    __shared__ float red[4];
    int cnt = rcnt[r];
    if (threadIdx.x < cnt) {
        cs[threadIdx.x] = cols[r * CAP + threadIdx.x] * NH;
        vsh[threadIdx.x] = vals[r * CAP + threadIdx.x];
    }
    __syncthreads();
    int c = threadIdx.x * 2;
    float2 acc = {0.f, 0.f};
    int j = 0;
    for (; j + 2 <= cnt; j += 2) {
        int c0 = cs[j], c1 = cs[j + 1];
        float v0 = vsh[j], v1 = vsh[j + 1];
        float2 wa = *(const float2*)(h + (size_t)c0 + c);
        float2 wb = *(const float2*)(h + (size_t)c1 + c);
        acc.x = fmaf(v0, wa.x, acc.x); acc.y = fmaf(v0, wa.y, acc.y);
        acc.x = fmaf(v1, wb.x, acc.x); acc.y = fmaf(v1, wb.y, acc.y);
    }
    if (j < cnt) {
        float2 wa = *(const float2*)(h + (size_t)cs[j] + c);
        acc.x = fmaf(vsh[j], wa.x, acc.x); acc.y = fmaf(vsh[j], wa.y, acc.y);
    }
    *(float2*)(g + (size_t)r * NH + c) = acc;
    float2 wq = *(const float2*)(w2q + c);
    float pp = acc.x * wq.x + acc.y * wq.y;
    for (int o = 32; o > 0; o >>= 1) pp += __shfl_down(pp, o);
    if ((threadIdx.x & 63) == 0) red[threadIdx.x >> 6] = pp;
    __syncthreads();
    if (threadIdx.x == 0) logits[r] = red[0] + red[1] + red[2] + red[3];
}

// ---------------------------------------------------------------------------
// KC: Ppart[vs] = mvmh_chunk @ g_chunk (lanes 0..49), Epart[vs] = aw_e_chunk @
//     g_chunk (lane 50 -- softmax weights stored as row 50 of the LDS tile,
//     halving the per-iter fma count vs computing E redundantly on all lanes).
//     s = rowsum(mvmh). g fetched as wave-uniform broadcast float4.
__global__ void kC_PE(const float* __restrict__ mvmh, const float* __restrict__ g,
                      const float* __restrict__ logits, float* __restrict__ Ppart,
                      float* __restrict__ Epart, float* __restrict__ s) {
    __shared__ float mvs[(NM + 1) * (VCH + 1)];
    __shared__ float red[4];
    int cb = blockIdx.x & (CB - 1);
    int vs = blockIdx.x / CB;
    int v0 = vs * VCH;
    int tid = threadIdx.x;

    for (int i = tid; i < NM * VCH; i += 256) {
        int m = i / VCH, vv = i - m * VCH;
        mvs[m * (VCH + 1) + vv] = mvmh[(size_t)m * NV + v0 + vv];
    }
    // block-redundant softmax scalars over logits[0..3999]
    float lmx = -1e30f;
    for (int i = tid; i < NV; i += 256) lmx = fmaxf(lmx, logits[i]);
    for (int o = 32; o > 0; o >>= 1) lmx = fmaxf(lmx, __shfl_xor(lmx, o));
    if ((tid & 63) == 0) red[tid >> 6] = lmx;
    __syncthreads();
    float mx = fmaxf(fmaxf(red[0], red[1]), fmaxf(red[2], red[3]));
    __syncthreads();
    float lsum = 0.f;
    for (int i = tid; i < NV; i += 256) lsum += __expf(logits[i] - mx);
    for (int o = 32; o > 0; o >>= 1) lsum += __shfl_xor(lsum, o);
    if ((tid & 63) == 0) red[tid >> 6] = lsum;
    __syncthreads();
    float inv = 1.f / (red[0] + red[1] + red[2] + red[3]);
    // e-weights for this v-chunk -> row 50 of the tile (lane 50 consumes it)
    for (int i = tid; i < VCH; i += 256)
        mvs[NM * (VCH + 1) + i] = __expf(logits[v0 + i] - mx) * inv;
    __syncthreads();

    int w = tid >> 6, l = tid & 63;
    int C = cb * 32 + w * 8;
    int lc = (l <= NM) ? l : 0;
    const float* mrow = mvs + lc * (VCH + 1);
    float acc[8];
    float accs = 0.f;
#pragma unroll
    for (int i = 0; i < 8; ++i) acc[i] = 0.f;
    for (int vv = 0; vv < VCH; ++vv) {
        int v = v0 + vv;
        float t = mrow[vv];
        float4 ga = *(const float4*)(g + (size_t)v * NH + C);
        float4 gb = *(const float4*)(g + (size_t)v * NH + C + 4);
        acc[0] = fmaf(t, ga.x, acc[0]);
        acc[1] = fmaf(t, ga.y, acc[1]);
        acc[2] = fmaf(t, ga.z, acc[2]);
        acc[3] = fmaf(t, ga.w, acc[3]);
        acc[4] = fmaf(t, gb.x, acc[4]);
        acc[5] = fmaf(t, gb.y, acc[5]);
        acc[6] = fmaf(t, gb.z, acc[6]);
        acc[7] = fmaf(t, gb.w, acc[7]);
        accs += t;
    }
    if (l < NM) {
        float* dst = Ppart + ((size_t)vs * NM + l) * NH + C;
        float4 o0 = {acc[0], acc[1], acc[2], acc[3]};
        float4 o1 = {acc[4], acc[5], acc[6], acc[7]};
        *(float4*)dst = o0;
        *(float4*)(dst + 4) = o1;
    } else if (l == NM) {
        float* dst = Epart + (size_t)vs * NH + C;
        float4 e0 = {acc[0], acc[1], acc[2], acc[3]};
        float4 e1 = {acc[4], acc[5], acc[6], acc[7]};
        *(float4*)dst = e0;
        *(float4*)(dst + 4) = e1;
    }
    if (cb == 0 && w == 0 && l < NM) atomicAdd(&s[l], accs);
}

// ---------------------------------------------------------------------------
// KT: fused tail = {rowsW2+KQG} -> barrier -> {hops/feat + gemv1} -> barrier
//     -> {gemv2}. 128 blocks <= 256 CUs (>=8 blocks/CU capacity) so all blocks
//     are co-resident; grid sync via device-scope atomic arrive + spin.
//     sync[0..1] zero-initialized by kA each replay.
__global__ __launch_bounds__(256) void kT_tail(
    const float* __restrict__ Ppart, const float* __restrict__ Epart,
    const float* __restrict__ W2, const float* __restrict__ b2,
    const float* __restrict__ s, const float* __restrict__ query,
    const float* __restrict__ keys, const float* __restrict__ Wo1,
    const float* __restrict__ bo1, const float* __restrict__ Wo2,
    float* __restrict__ R, float* __restrict__ ctxE, float* __restrict__ G,
    float* __restrict__ KQ, float* __restrict__ hid, float* __restrict__ out,
    int* __restrict__ sync) {
    int bid = blockIdx.x, tid = threadIdx.x;
    __shared__ float xs[NH];
    __shared__ float ys[NH];
    __shared__ float Gs[NM * NM];
    __shared__ float aws[NM];
    __shared__ float As[NM];
    __shared__ float fs[64];
    __shared__ float rh[128];

    // ---------------- phase 1: reduce partials; R/ctxE = row @ W2; G/KQ ----
    if (bid < NM + 1) {
        int m = bid;
        if (m < NM) {
            for (int k = tid; k < NH; k += 256) {
                float v = 0.f;
                const float* p = Ppart + (size_t)m * NH + k;
                for (int q = 0; q < VS; ++q) v += p[(size_t)q * NM * NH];
                xs[k] = v;
            }
        } else {
            for (int k = tid; k < NH; k += 256) {
                float v = 0.f;
                for (int q = 0; q < VS; ++q) v += Epart[(size_t)q * NH + k];
                xs[k] = v;
            }
        }
        __syncthreads();
        int c = tid * 2;
        float2 acc = {0.f, 0.f};
        const float4* xs4 = (const float4*)xs;
        for (int kk = 0; kk < NH / 4; ++kk) {
            float4 x = xs4[kk];
            int k = kk * 4;
            float2 w0 = *(const float2*)(W2 + (size_t)k * NH + c);
            float2 w1 = *(const float2*)(W2 + (size_t)(k + 1) * NH + c);
            float2 w2v = *(const float2*)(W2 + (size_t)(k + 2) * NH + c);
            float2 w3 = *(const float2*)(W2 + (size_t)(k + 3) * NH + c);
            acc.x = fmaf(x.x, w0.x, acc.x);  acc.y = fmaf(x.x, w0.y, acc.y);
            acc.x = fmaf(x.y, w1.x, acc.x);  acc.y = fmaf(x.y, w1.y, acc.y);
            acc.x = fmaf(x.z, w2v.x, acc.x); acc.y = fmaf(x.z, w2v.y, acc.y);
            acc.x = fmaf(x.w, w3.x, acc.x);  acc.y = fmaf(x.w, w3.y, acc.y);
        }
        float2 bb = *(const float2*)(b2 + c);
        if (m < NM) {
            float sm = s[m];
            acc.x += sm * bb.x;
            acc.y += sm * bb.y;
            *(float2*)(R + (size_t)m * NH + c) = acc;
            ys[c] = acc.x; ys[c + 1] = acc.y;
        } else {
            acc.x += bb.x;
            acc.y += bb.y;
            *(float2*)(ctxE + c) = acc;
            float2 q2 = *(const float2*)(query + c);
            ys[c] = q2.x; ys[c + 1] = q2.y;
        }
        __syncthreads();
        int wid = tid >> 6, lane = tid & 63;
        for (int mm = wid; mm < NM; mm += 4) {
            const float* kr = keys + (size_t)mm * NH;
            float p = 0.f;
            for (int jj = lane; jj < NH; jj += 64) p = fmaf(kr[jj], ys[jj], p);
            for (int o = 32; o > 0; o >>= 1) p += __shfl_down(p, o);
            if (lane == 0) {
                if (m < NM) G[m * NM + mm] = p;
                else KQ[mm] = p;
            }
        }
    }
    // ---- barrier 1 ----
    __threadfence();
    __syncthreads();
    if (tid == 0) {
        __hip_atomic_fetch_add(&sync[0], 1, __ATOMIC_ACQ_REL, __HIP_MEMORY_SCOPE_AGENT);
        while (__hip_atomic_load(&sync[0], __ATOMIC_ACQUIRE, __HIP_MEMORY_SCOPE_AGENT) < TGRID)
            __builtin_amdgcn_s_sleep(8);
    }
    __syncthreads();
    __threadfence();

    // ---------------- phase 2: hops/feat + hid += fs @ Wo1 ----------------
    if (bid < 96) {
        int ks = bid >> 2, jt = bid & 3;
        int k0 = ks * 64;
        int seg = k0 >> 9;   // 0: query, 1: context_o, 2: ctxE
        if (seg == 1) {
            for (int i = tid; i < NM * NM; i += 256) Gs[i] = G[i];
            __syncthreads();
            if (tid < 64) {
                int l = tid;
                float L = (l < NM) ? KQ[l] : -1e30f;
                float Aacc = 0.f;
                for (int t = 0; t < NHOPS; ++t) {
                    float mxv = L;
                    for (int o = 32; o > 0; o >>= 1) mxv = fmaxf(mxv, __shfl_xor(mxv, o));
                    float e = (l < NM) ? __expf(L - mxv) : 0.f;
                    float sm = e;
                    for (int o = 32; o > 0; o >>= 1) sm += __shfl_xor(sm, o);
                    float aw = e / sm;
                    Aacc += aw;
                    if (l < NM) aws[l] = aw;       // intra-wave LDS, hw-ordered
                    if (l < NM) {
                        float d = 0.f;
                        for (int mp = 0; mp < NM; ++mp) d = fmaf(aws[mp], Gs[mp * NM + l], d);
                        L += d;
                    }
                }
                if (l < NM) As[l] = Aacc;
            }
            __syncthreads();
            if (tid < 64) {
                int kk = k0 + tid - NH;            // 0..511
                float v = query[kk];
                for (int mp = 0; mp < NM; ++mp) v = fmaf(As[mp], R[mp * NH + kk], v);
                fs[tid] = fmaxf(v, 0.f);
            }
        } else if (seg == 0) {
            if (tid < 64) fs[tid] = fmaxf(query[k0 + tid], 0.f);
        } else {
            if (tid < 64) fs[tid] = fmaxf(ctxE[k0 + tid - 2 * NH], 0.f);
        }
        __syncthreads();
        int j = jt * 256 + tid;
        float acc = 0.f;
        const float4* fs4 = (const float4*)fs;
#pragma unroll
        for (int ii = 0; ii < 16; ++ii) {
            float4 f = fs4[ii];
            int k = k0 + ii * 4;
            acc = fmaf(f.x, Wo1[(size_t)k * 1024 + j], acc);
            acc = fmaf(f.y, Wo1[(size_t)(k + 1) * 1024 + j], acc);
            acc = fmaf(f.z, Wo1[(size_t)(k + 2) * 1024 + j], acc);
            acc = fmaf(f.w, Wo1[(size_t)(k + 3) * 1024 + j], acc);
        }
        atomicAdd(&hid[j], acc);
    }
    // ---- barrier 2 ----
    __threadfence();
    __syncthreads();
    if (tid == 0) {
        __hip_atomic_fetch_add(&sync[1], 1, __ATOMIC_ACQ_REL, __HIP_MEMORY_SCOPE_AGENT);
        while (__hip_atomic_load(&sync[1], __ATOMIC_ACQUIRE, __HIP_MEMORY_SCOPE_AGENT) < TGRID)
            __builtin_amdgcn_s_sleep(8);
    }
    __syncthreads();
    __threadfence();

    // ---------------- phase 3: out += relu(hid + bo1) @ Wo2 ----------------
    {
        int ks2 = bid >> 4;        // 0..7, k-split of 128
        int vt = bid & 15;         // 0..15, 256-col strip
        int k0 = ks2 * 128;
        if (tid < 128) rh[tid] = fmaxf(hid[k0 + tid] + bo1[k0 + tid], 0.f);
        __syncthreads();
        int v = vt * 256 + tid;
        if (v < NV) {
            float acc = 0.f;
            const float4* rh4 = (const float4*)rh;
#pragma unroll
            for (int ii = 0; ii < 32; ++ii) {
                float4 f = rh4[ii];
                int k = k0 + ii * 4;
                acc = fmaf(f.x, Wo2[(size_t)k * NV + v], acc);
                acc = fmaf(f.y, Wo2[(size_t)(k + 1) * NV + v], acc);
                acc = fmaf(f.z, Wo2[(size_t)(k + 2) * NV + v], acc);
                acc = fmaf(f.w, Wo2[(size_t)(k + 3) * NV + v], acc);
            }
            atomicAdd(&out[v], acc);
        }
    }
}

// ---------------------------------------------------------------------------
extern "C" void kernel_launch(void* const* d_in, const int* in_sizes, int n_in,
                              void* d_out, int out_size, void* d_ws, size_t ws_size,
                              hipStream_t stream) {
    const float* query = (const float*)d_in[0];
    const float* keys  = (const float*)d_in[1];
    const float* mvmh  = (const float*)d_in[2];
    const float* adj   = (const float*)d_in[3];
    const float* W1    = (const float*)d_in[4];
    const float* b1    = (const float*)d_in[5];
    const float* W2    = (const float*)d_in[6];
    const float* b2    = (const float*)d_in[7];
    const float* Wo1   = (const float*)d_in[8];
    const float* bo1   = (const float*)d_in[9];
    const float* Wo2   = (const float*)d_in[10];
    const float* bo2   = (const float*)d_in[11];
    float* out = (float*)d_out;

    char* w = (char*)d_ws;
    int* rcnt = (int*)w;        w += 4096 * 4;
    int* cols = (int*)w;        w += NV * CAP * 4;
    float* vals = (float*)w;    w += NV * CAP * 4;
    float* h = (float*)w;       w += (size_t)NV * NH * 4;
    float* g = (float*)w;       w += (size_t)NV * NH * 4;
    float* logits = (float*)w;  w += 4096 * 4;
    float* w2q = (float*)w;     w += NH * 4;
    float* Ppart = (float*)w;   w += (size_t)VS * NM * NH * 4;   // 640000 floats
    float* Epart = (float*)w;   w += VS * NH * 4;                // 12800 floats
    float* zreg = (float*)w;                                     // s+hid+sync (1152 floats)
    float* s = (float*)w;       w += 64 * 4;
    float* hid = (float*)w;     w += 1024 * 4;
    int* syncc = (int*)w;       w += 64 * 4;
    float* R = (float*)w;       w += NM * NH * 4;
    float* ctxE = (float*)w;    w += NH * 4;
    float* G = (float*)w;       w += 2560 * 4;
    float* KQ = (float*)w;      w += 64 * 4;

    kA_csr_h<<<NV + 128 + 16, 256, 0, stream>>>(adj, query, W1, b1, W2, bo2,
                                                rcnt, cols, vals, h, w2q, zreg, out);
    kB_spmm_g<<<NV, 256, 0, stream>>>(rcnt, cols, vals, h, w2q, g, logits);
    kC_PE<<<CB * VS, 256, 0, stream>>>(mvmh, g, logits, Ppart, Epart, s);
    kT_tail<<<TGRID, 256, 0, stream>>>(Ppart, Epart, W2, b2, s, query, keys,
                                       Wo1, bo1, Wo2, R, ctxE, G, KQ, hid, out, syncc);
}

// Round 5
// 261.838 us; speedup vs baseline: 1.2091x; 1.2091x over previous
//
#include <hip/hip_runtime.h>

// Problem constants (fixed by reference)
#define NV 4000
#define NH 512
#define NM 50
#define CAP 96
#define NHOPS 6
#define VS 25          // v-splits in kC
#define VCH 160        // NV / VS
#define CB 16          // c-chunk blocks in kC (32 cols per block, 8 per wave)
#define TGRID 128      // tail-kernel grid (<=256 CUs -> all co-resident)
#define NP1 (NM + 1)   // phase-1 producer blocks
#define NP2 96         // phase-2 producer blocks

// ---------------------------------------------------------------------------
// KA: b<4000: CSR build (float4 scan) + immediately h[r] = relu(row@W1 + b1).
//     b in [4000,4128): w2q = W2 @ q.  b >= 4128: out = bo2, zero s/hid/sync.
__global__ void kA_csr_h(const float* __restrict__ adj, const float* __restrict__ query,
                         const float* __restrict__ W1, const float* __restrict__ b1,
                         const float* __restrict__ W2, const float* __restrict__ bo2,
                         int* __restrict__ rcnt, int* __restrict__ cols, float* __restrict__ vals,
                         float* __restrict__ h, float* __restrict__ w2q,
                         float* __restrict__ zreg, float* __restrict__ out) {
    int b = blockIdx.x;
    if (b < NV) {
        __shared__ int cnt;
        __shared__ int cs[CAP];
        __shared__ float vsh[CAP];
        if (threadIdx.x == 0) cnt = 0;
        __syncthreads();
        const float4* row4 = (const float4*)(adj + (size_t)b * NV);
        for (int i = threadIdx.x; i < NV / 4; i += 256) {
            float4 a = row4[i];
            if (a.x != 0.f) { int k = atomicAdd(&cnt, 1); if (k < CAP) { cs[k] = 4*i;   vsh[k] = a.x; } }
            if (a.y != 0.f) { int k = atomicAdd(&cnt, 1); if (k < CAP) { cs[k] = 4*i+1; vsh[k] = a.y; } }
            if (a.z != 0.f) { int k = atomicAdd(&cnt, 1); if (k < CAP) { cs[k] = 4*i+2; vsh[k] = a.z; } }
            if (a.w != 0.f) { int k = atomicAdd(&cnt, 1); if (k < CAP) { cs[k] = 4*i+3; vsh[k] = a.w; } }
        }
        __syncthreads();
        int n = cnt < CAP ? cnt : CAP;
        if (threadIdx.x == 0) rcnt[b] = n;
        if (threadIdx.x < n) {
            cols[b * CAP + threadIdx.x] = cs[threadIdx.x];
            vals[b * CAP + threadIdx.x] = vsh[threadIdx.x];
        }
        int c = threadIdx.x * 2;
        float2 acc = *(const float2*)(b1 + c);
        int j = 0;
        for (; j + 2 <= n; j += 2) {
            int c0 = cs[j], c1 = cs[j + 1];
            float v0 = vsh[j], v1 = vsh[j + 1];
            float2 wa = *(const float2*)(W1 + (size_t)c0 * NH + c);
            float2 wb = *(const float2*)(W1 + (size_t)c1 * NH + c);
            acc.x = fmaf(v0, wa.x, acc.x); acc.y = fmaf(v0, wa.y, acc.y);
            acc.x = fmaf(v1, wb.x, acc.x); acc.y = fmaf(v1, wb.y, acc.y);
        }
        if (j < n) {
            float2 wa = *(const float2*)(W1 + (size_t)cs[j] * NH + c);
            acc.x = fmaf(vsh[j], wa.x, acc.x); acc.y = fmaf(vsh[j], wa.y, acc.y);
        }
        float2 o = {fmaxf(acc.x, 0.f), fmaxf(acc.y, 0.f)};
        *(float2*)(h + (size_t)b * NH + c) = o;
    } else if (b < NV + 128) {
        __shared__ float qs[NH];
        qs[threadIdx.x] = query[threadIdx.x];
        qs[threadIdx.x + 256] = query[threadIdx.x + 256];
        __syncthreads();
        int wid = threadIdx.x >> 6, lane = threadIdx.x & 63;
        int k = (b - NV) * 4 + wid;
        const float* wr = W2 + (size_t)k * NH;
        float p = 0.f;
        for (int j = lane; j < NH; j += 64) p = fmaf(wr[j], qs[j], p);
        for (int o = 32; o > 0; o >>= 1) p += __shfl_down(p, o);
        if (lane == 0) w2q[k] = p;
    } else {
        int t = (b - NV - 128) * 256 + threadIdx.x;   // 0..4095
        if (t < NV) out[t] = bo2[t];
        if (t < 1152) zreg[t] = 0.f;                  // s[64] + hid[1024] + sync[64]
    }
}

// ---------------------------------------------------------------------------
// KB: g = spmm(adj, h); fused logits[r] = dot(g[r,:], w2q)  (unroll-2 gather)
__global__ void kB_spmm_g(const int* __restrict__ rcnt, const int* __restrict__ cols,
                          const float* __restrict__ vals, const float* __restrict__ h,
                          const float* __restrict__ w2q, float* __restrict__ g,
                          float* __restrict__ logits) {
    int r = blockIdx.x;
    __shared__ int cs[CAP];
    __shared__ float vsh[CAP];
    __shared__ float red[4];
    int cnt = rcnt[r];
    if (threadIdx.x < cnt) {
        cs[threadIdx.x] = cols[r * CAP + threadIdx.x] * NH;
        vsh[threadIdx.x] = vals[r * CAP + threadIdx.x];
    }
    __syncthreads();
    int c = threadIdx.x * 2;
    float2 acc = {0.f, 0.f};
    int j = 0;
    for (; j + 2 <= cnt; j += 2) {
        int c0 = cs[j], c1 = cs[j + 1];
        float v0 = vsh[j], v1 = vsh[j + 1];
        float2 wa = *(const float2*)(h + (size_t)c0 + c);
        float2 wb = *(const float2*)(h + (size_t)c1 + c);
        acc.x = fmaf(v0, wa.x, acc.x); acc.y = fmaf(v0, wa.y, acc.y);
        acc.x = fmaf(v1, wb.x, acc.x); acc.y = fmaf(v1, wb.y, acc.y);
    }
    if (j < cnt) {
        float2 wa = *(const float2*)(h + (size_t)cs[j] + c);
        acc.x = fmaf(vsh[j], wa.x, acc.x); acc.y = fmaf(vsh[j], wa.y, acc.y);
    }
    *(float2*)(g + (size_t)r * NH + c) = acc;
    float2 wq = *(const float2*)(w2q + c);
    float pp = acc.x * wq.x + acc.y * wq.y;
    for (int o = 32; o > 0; o >>= 1) pp += __shfl_down(pp, o);
    if ((threadIdx.x & 63) == 0) red[threadIdx.x >> 6] = pp;
    __syncthreads();
    if (threadIdx.x == 0) logits[r] = red[0] + red[1] + red[2] + red[3];
}

// ---------------------------------------------------------------------------
// KC: Ppart[vs] = mvmh_chunk @ g_chunk (lanes 0..49), Epart[vs] = aw_e_chunk @
//     g_chunk (lane 50 -- softmax weights stored as row 50 of the LDS tile).
//     s = rowsum(mvmh). g fetched as wave-uniform broadcast float4.
__global__ void kC_PE(const float* __restrict__ mvmh, const float* __restrict__ g,
                      const float* __restrict__ logits, float* __restrict__ Ppart,
                      float* __restrict__ Epart, float* __restrict__ s) {
    __shared__ float mvs[(NM + 1) * (VCH + 1)];
    __shared__ float red[4];
    int cb = blockIdx.x & (CB - 1);
    int vs = blockIdx.x / CB;
    int v0 = vs * VCH;
    int tid = threadIdx.x;

    for (int i = tid; i < NM * VCH; i += 256) {
        int m = i / VCH, vv = i - m * VCH;
        mvs[m * (VCH + 1) + vv] = mvmh[(size_t)m * NV + v0 + vv];
    }
    // block-redundant softmax scalars over logits[0..3999]
    float lmx = -1e30f;
    for (int i = tid; i < NV; i += 256) lmx = fmaxf(lmx, logits[i]);
    for (int o = 32; o > 0; o >>= 1) lmx = fmaxf(lmx, __shfl_xor(lmx, o));
    if ((tid & 63) == 0) red[tid >> 6] = lmx;
    __syncthreads();
    float mx = fmaxf(fmaxf(red[0], red[1]), fmaxf(red[2], red[3]));
    __syncthreads();
    float lsum = 0.f;
    for (int i = tid; i < NV; i += 256) lsum += __expf(logits[i] - mx);
    for (int o = 32; o > 0; o >>= 1) lsum += __shfl_xor(lsum, o);
    if ((tid & 63) == 0) red[tid >> 6] = lsum;
    __syncthreads();
    float inv = 1.f / (red[0] + red[1] + red[2] + red[3]);
    for (int i = tid; i < VCH; i += 256)
        mvs[NM * (VCH + 1) + i] = __expf(logits[v0 + i] - mx) * inv;
    __syncthreads();

    int w = tid >> 6, l = tid & 63;
    int C = cb * 32 + w * 8;
    int lc = (l <= NM) ? l : 0;
    const float* mrow = mvs + lc * (VCH + 1);
    float acc[8];
    float accs = 0.f;
#pragma unroll
    for (int i = 0; i < 8; ++i) acc[i] = 0.f;
    for (int vv = 0; vv < VCH; ++vv) {
        int v = v0 + vv;
        float t = mrow[vv];
        float4 ga = *(const float4*)(g + (size_t)v * NH + C);
        float4 gb = *(const float4*)(g + (size_t)v * NH + C + 4);
        acc[0] = fmaf(t, ga.x, acc[0]);
        acc[1] = fmaf(t, ga.y, acc[1]);
        acc[2] = fmaf(t, ga.z, acc[2]);
        acc[3] = fmaf(t, ga.w, acc[3]);
        acc[4] = fmaf(t, gb.x, acc[4]);
        acc[5] = fmaf(t, gb.y, acc[5]);
        acc[6] = fmaf(t, gb.z, acc[6]);
        acc[7] = fmaf(t, gb.w, acc[7]);
        accs += t;
    }
    if (l < NM) {
        float* dst = Ppart + ((size_t)vs * NM + l) * NH + C;
        float4 o0 = {acc[0], acc[1], acc[2], acc[3]};
        float4 o1 = {acc[4], acc[5], acc[6], acc[7]};
        *(float4*)dst = o0;
        *(float4*)(dst + 4) = o1;
    } else if (l == NM) {
        float* dst = Epart + (size_t)vs * NH + C;
        float4 e0 = {acc[0], acc[1], acc[2], acc[3]};
        float4 e1 = {acc[4], acc[5], acc[6], acc[7]};
        *(float4*)dst = e0;
        *(float4*)(dst + 4) = e1;
    }
    if (cb == 0 && w == 0 && l < NM) atomicAdd(&s[l], accs);
}

// ---------------------------------------------------------------------------
// KT: fused tail = {rowsW2+KQG} -> flag -> {hops/feat + gemv1} -> flag ->
//     {gemv2}. 128 blocks co-resident. Sync protocol (the R4 barrier was a
//     coherence DoS: per-poll ACQUIRE loads + __threadfence invalidated L2
//     continuously): producers do ONE release-add after __syncthreads;
//     consumers spin on RELAXED loads (no invalidation) + s_sleep backoff,
//     then ONE acquire load after the flag trips. No __threadfence anywhere.
__global__ __launch_bounds__(256) void kT_tail(
    const float* __restrict__ Ppart, const float* __restrict__ Epart,
    const float* __restrict__ W2, const float* __restrict__ b2,
    const float* __restrict__ s, const float* __restrict__ query,
    const float* __restrict__ keys, const float* __restrict__ Wo1,
    const float* __restrict__ bo1, const float* __restrict__ Wo2,
    float* __restrict__ R, float* __restrict__ ctxE, float* __restrict__ G,
    float* __restrict__ KQ, float* __restrict__ hid, float* __restrict__ out,
    int* __restrict__ sync) {
    int bid = blockIdx.x, tid = threadIdx.x;
    __shared__ float xs[NH];
    __shared__ float ys[NH];
    __shared__ float Gs[NM * NM];
    __shared__ float aws[NM];
    __shared__ float As[NM];
    __shared__ float fs[64];
    __shared__ float rh[128];

    // ---------------- phase 1: reduce partials; R/ctxE = row @ W2; G/KQ ----
    if (bid < NP1) {
        int m = bid;
        if (m < NM) {
            for (int k = tid; k < NH; k += 256) {
                float v = 0.f;
                const float* p = Ppart + (size_t)m * NH + k;
                for (int q = 0; q < VS; ++q) v += p[(size_t)q * NM * NH];
                xs[k] = v;
            }
        } else {
            for (int k = tid; k < NH; k += 256) {
                float v = 0.f;
                for (int q = 0; q < VS; ++q) v += Epart[(size_t)q * NH + k];
                xs[k] = v;
            }
        }
        __syncthreads();
        int c = tid * 2;
        float2 acc = {0.f, 0.f};
        const float4* xs4 = (const float4*)xs;
        for (int kk = 0; kk < NH / 4; ++kk) {
            float4 x = xs4[kk];
            int k = kk * 4;
            float2 w0 = *(const float2*)(W2 + (size_t)k * NH + c);
            float2 w1 = *(const float2*)(W2 + (size_t)(k + 1) * NH + c);
            float2 w2v = *(const float2*)(W2 + (size_t)(k + 2) * NH + c);
            float2 w3 = *(const float2*)(W2 + (size_t)(k + 3) * NH + c);
            acc.x = fmaf(x.x, w0.x, acc.x);  acc.y = fmaf(x.x, w0.y, acc.y);
            acc.x = fmaf(x.y, w1.x, acc.x);  acc.y = fmaf(x.y, w1.y, acc.y);
            acc.x = fmaf(x.z, w2v.x, acc.x); acc.y = fmaf(x.z, w2v.y, acc.y);
            acc.x = fmaf(x.w, w3.x, acc.x);  acc.y = fmaf(x.w, w3.y, acc.y);
        }
        float2 bb = *(const float2*)(b2 + c);
        if (m < NM) {
            float sm = s[m];
            acc.x += sm * bb.x;
            acc.y += sm * bb.y;
            *(float2*)(R + (size_t)m * NH + c) = acc;
            ys[c] = acc.x; ys[c + 1] = acc.y;
        } else {
            acc.x += bb.x;
            acc.y += bb.y;
            *(float2*)(ctxE + c) = acc;
            float2 q2 = *(const float2*)(query + c);
            ys[c] = q2.x; ys[c + 1] = q2.y;
        }
        __syncthreads();
        int wid = tid >> 6, lane = tid & 63;
        for (int mm = wid; mm < NM; mm += 4) {
            const float* kr = keys + (size_t)mm * NH;
            float p = 0.f;
            for (int jj = lane; jj < NH; jj += 64) p = fmaf(kr[jj], ys[jj], p);
            for (int o = 32; o > 0; o >>= 1) p += __shfl_down(p, o);
            if (lane == 0) {
                if (m < NM) G[m * NM + mm] = p;
                else KQ[mm] = p;
            }
        }
        __syncthreads();   // drain all stores before the release-add
        if (tid == 0)
            __hip_atomic_fetch_add(&sync[0], 1, __ATOMIC_RELEASE, __HIP_MEMORY_SCOPE_AGENT);
    }

    // ---------------- phase 2: hops/feat + hid += fs @ Wo1 ----------------
    if (bid < NP2) {
        if (tid == 0) {
            while (__hip_atomic_load(&sync[0], __ATOMIC_RELAXED, __HIP_MEMORY_SCOPE_AGENT) < NP1)
                __builtin_amdgcn_s_sleep(2);
            (void)__hip_atomic_load(&sync[0], __ATOMIC_ACQUIRE, __HIP_MEMORY_SCOPE_AGENT);
        }
        __syncthreads();
        int ks = bid >> 2, jt = bid & 3;
        int k0 = ks * 64;
        int seg = k0 >> 9;   // 0: query, 1: context_o, 2: ctxE
        if (seg == 1) {
            for (int i = tid; i < NM * NM; i += 256) Gs[i] = G[i];
            __syncthreads();
            if (tid < 64) {
                int l = tid;
                float L = (l < NM) ? KQ[l] : -1e30f;
                float Aacc = 0.f;
                for (int t = 0; t < NHOPS; ++t) {
                    float mxv = L;
                    for (int o = 32; o > 0; o >>= 1) mxv = fmaxf(mxv, __shfl_xor(mxv, o));
                    float e = (l < NM) ? __expf(L - mxv) : 0.f;
                    float sm = e;
                    for (int o = 32; o > 0; o >>= 1) sm += __shfl_xor(sm, o);
                    float aw = e / sm;
                    Aacc += aw;
                    if (l < NM) aws[l] = aw;       // intra-wave LDS, hw-ordered
                    if (l < NM) {
                        float d = 0.f;
                        for (int mp = 0; mp < NM; ++mp) d = fmaf(aws[mp], Gs[mp * NM + l], d);
                        L += d;
                    }
                }
                if (l < NM) As[l] = Aacc;
            }
            __syncthreads();
            if (tid < 64) {
                int kk = k0 + tid - NH;            // 0..511
                float v = query[kk];
                for (int mp = 0; mp < NM; ++mp) v = fmaf(As[mp], R[mp * NH + kk], v);
                fs[tid] = fmaxf(v, 0.f);
            }
        } else if (seg == 0) {
            if (tid < 64) fs[tid] = fmaxf(query[k0 + tid], 0.f);
        } else {
            if (tid < 64) fs[tid] = fmaxf(ctxE[k0 + tid - 2 * NH], 0.f);
        }
        __syncthreads();
        int j = jt * 256 + tid;
        float acc = 0.f;
        const float4* fs4 = (const float4*)fs;
#pragma unroll
        for (int ii = 0; ii < 16; ++ii) {
            float4 f = fs4[ii];
            int k = k0 + ii * 4;
            acc = fmaf(f.x, Wo1[(size_t)k * 1024 + j], acc);
            acc = fmaf(f.y, Wo1[(size_t)(k + 1) * 1024 + j], acc);
            acc = fmaf(f.z, Wo1[(size_t)(k + 2) * 1024 + j], acc);
            acc = fmaf(f.w, Wo1[(size_t)(k + 3) * 1024 + j], acc);
        }
        atomicAdd(&hid[j], acc);                  // device-scope, lands coherent
        __syncthreads();                          // drain atomics before release
        if (tid == 0)
            __hip_atomic_fetch_add(&sync[1], 1, __ATOMIC_RELEASE, __HIP_MEMORY_SCOPE_AGENT);
    }

    // ---------------- phase 3: out += relu(hid + bo1) @ Wo2 ----------------
    if (tid == 0) {
        while (__hip_atomic_load(&sync[1], __ATOMIC_RELAXED, __HIP_MEMORY_SCOPE_AGENT) < NP2)
            __builtin_amdgcn_s_sleep(2);
        (void)__hip_atomic_load(&sync[1], __ATOMIC_ACQUIRE, __HIP_MEMORY_SCOPE_AGENT);
    }
    __syncthreads();
    {
        int ks2 = bid >> 4;        // 0..7, k-split of 128
        int vt = bid & 15;         // 0..15, 256-col strip
        int k0 = ks2 * 128;
        if (tid < 128) rh[tid] = fmaxf(hid[k0 + tid] + bo1[k0 + tid], 0.f);
        __syncthreads();
        int v = vt * 256 + tid;
        if (v < NV) {
            float acc = 0.f;
            const float4* rh4 = (const float4*)rh;
#pragma unroll
            for (int ii = 0; ii < 32; ++ii) {
                float4 f = rh4[ii];
                int k = k0 + ii * 4;
                acc = fmaf(f.x, Wo2[(size_t)k * NV + v], acc);
                acc = fmaf(f.y, Wo2[(size_t)(k + 1) * NV + v], acc);
                acc = fmaf(f.z, Wo2[(size_t)(k + 2) * NV + v], acc);
                acc = fmaf(f.w, Wo2[(size_t)(k + 3) * NV + v], acc);
            }
            atomicAdd(&out[v], acc);
        }
    }
}

// ---------------------------------------------------------------------------
extern "C" void kernel_launch(void* const* d_in, const int* in_sizes, int n_in,
                              void* d_out, int out_size, void* d_ws, size_t ws_size,
                              hipStream_t stream) {
    const float* query = (const float*)d_in[0];
    const float* keys  = (const float*)d_in[1];
    const float* mvmh  = (const float*)d_in[2];
    const float* adj   = (const float*)d_in[3];
    const float* W1    = (const float*)d_in[4];
    const float* b1    = (const float*)d_in[5];
    const float* W2    = (const float*)d_in[6];
    const float* b2    = (const float*)d_in[7];
    const float* Wo1   = (const float*)d_in[8];
    const float* bo1   = (const float*)d_in[9];
    const float* Wo2   = (const float*)d_in[10];
    const float* bo2   = (const float*)d_in[11];
    float* out = (float*)d_out;

    char* w = (char*)d_ws;
    int* rcnt = (int*)w;        w += 4096 * 4;
    int* cols = (int*)w;        w += NV * CAP * 4;
    float* vals = (float*)w;    w += NV * CAP * 4;
    float* h = (float*)w;       w += (size_t)NV * NH * 4;
    float* g = (float*)w;       w += (size_t)NV * NH * 4;
    float* logits = (float*)w;  w += 4096 * 4;
    float* w2q = (float*)w;     w += NH * 4;
    float* Ppart = (float*)w;   w += (size_t)VS * NM * NH * 4;   // 640000 floats
    float* Epart = (float*)w;   w += VS * NH * 4;                // 12800 floats
    float* zreg = (float*)w;                                     // s+hid+sync (1152 floats)
    float* s = (float*)w;       w += 64 * 4;
    float* hid = (float*)w;     w += 1024 * 4;
    int* syncc = (int*)w;       w += 64 * 4;
    float* R = (float*)w;       w += NM * NH * 4;
    float* ctxE = (float*)w;    w += NH * 4;
    float* G = (float*)w;       w += 2560 * 4;
    float* KQ = (float*)w;      w += 64 * 4;

    kA_csr_h<<<NV + 128 + 16, 256, 0, stream>>>(adj, query, W1, b1, W2, bo2,
                                                rcnt, cols, vals, h, w2q, zreg, out);
    kB_spmm_g<<<NV, 256, 0, stream>>>(rcnt, cols, vals, h, w2q, g, logits);
    kC_PE<<<CB * VS, 256, 0, stream>>>(mvmh, g, logits, Ppart, Epart, s);
    kT_tail<<<TGRID, 256, 0, stream>>>(Ppart, Epart, W2, b2, s, query, keys,
                                       Wo1, bo1, Wo2, R, ctxE, G, KQ, hid, out, syncc);
}

// Round 7
// 232.985 us; speedup vs baseline: 1.3588x; 1.1238x over previous
//
#include <hip/hip_runtime.h>

// Problem constants (fixed by reference)
#define NV 4000
#define NH 512
#define NM 50
#define CAP 96
#define NHOPS 6
#define VS 25          // v-splits in kC
#define VCH 160        // NV / VS
#define CB 16          // c-chunk blocks in kC (32 cols per block, 8 per wave)
#define TGRID 256      // tail-kernel grid (256 blocks x 4 waves -> always co-resident)
#define NP1 (NM + 1)   // phase-1 producer blocks
#define NP2 96         // phase-2 producer blocks

// ---------------------------------------------------------------------------
// KA: b<4000: CSR build (float4 scan) + immediately h[r] = relu(row@W1 + b1).
//     b in [4000,4128): w2q = W2 @ q.  b >= 4128: out = bo2, zero s/hid/sync.
__global__ void kA_csr_h(const float* __restrict__ adj, const float* __restrict__ query,
                         const float* __restrict__ W1, const float* __restrict__ b1,
                         const float* __restrict__ W2, const float* __restrict__ bo2,
                         int* __restrict__ rcnt, int* __restrict__ cols, float* __restrict__ vals,
                         float* __restrict__ h, float* __restrict__ w2q,
                         float* __restrict__ zreg, float* __restrict__ out) {
    int b = blockIdx.x;
    if (b < NV) {
        __shared__ int cnt;
        __shared__ int cs[CAP];
        __shared__ float vsh[CAP];
        if (threadIdx.x == 0) cnt = 0;
        __syncthreads();
        const float4* row4 = (const float4*)(adj + (size_t)b * NV);
        for (int i = threadIdx.x; i < NV / 4; i += 256) {
            float4 a = row4[i];
            if (a.x != 0.f) { int k = atomicAdd(&cnt, 1); if (k < CAP) { cs[k] = 4*i;   vsh[k] = a.x; } }
            if (a.y != 0.f) { int k = atomicAdd(&cnt, 1); if (k < CAP) { cs[k] = 4*i+1; vsh[k] = a.y; } }
            if (a.z != 0.f) { int k = atomicAdd(&cnt, 1); if (k < CAP) { cs[k] = 4*i+2; vsh[k] = a.z; } }
            if (a.w != 0.f) { int k = atomicAdd(&cnt, 1); if (k < CAP) { cs[k] = 4*i+3; vsh[k] = a.w; } }
        }
        __syncthreads();
        int n = cnt < CAP ? cnt : CAP;
        if (threadIdx.x == 0) rcnt[b] = n;
        if (threadIdx.x < n) {
            cols[b * CAP + threadIdx.x] = cs[threadIdx.x];
            vals[b * CAP + threadIdx.x] = vsh[threadIdx.x];
        }
        int c = threadIdx.x * 2;
        float2 acc = *(const float2*)(b1 + c);
        int j = 0;
        for (; j + 2 <= n; j += 2) {
            int c0 = cs[j], c1 = cs[j + 1];
            float v0 = vsh[j], v1 = vsh[j + 1];
            float2 wa = *(const float2*)(W1 + (size_t)c0 * NH + c);
            float2 wb = *(const float2*)(W1 + (size_t)c1 * NH + c);
            acc.x = fmaf(v0, wa.x, acc.x); acc.y = fmaf(v0, wa.y, acc.y);
            acc.x = fmaf(v1, wb.x, acc.x); acc.y = fmaf(v1, wb.y, acc.y);
        }
        if (j < n) {
            float2 wa = *(const float2*)(W1 + (size_t)cs[j] * NH + c);
            acc.x = fmaf(vsh[j], wa.x, acc.x); acc.y = fmaf(vsh[j], wa.y, acc.y);
        }
        float2 o = {fmaxf(acc.x, 0.f), fmaxf(acc.y, 0.f)};
        *(float2*)(h + (size_t)b * NH + c) = o;
    } else if (b < NV + 128) {
        __shared__ float qs[NH];
        qs[threadIdx.x] = query[threadIdx.x];
        qs[threadIdx.x + 256] = query[threadIdx.x + 256];
        __syncthreads();
        int wid = threadIdx.x >> 6, lane = threadIdx.x & 63;
        int k = (b - NV) * 4 + wid;
        const float* wr = W2 + (size_t)k * NH;
        float p = 0.f;
        for (int j = lane; j < NH; j += 64) p = fmaf(wr[j], qs[j], p);
        for (int o = 32; o > 0; o >>= 1) p += __shfl_down(p, o);
        if (lane == 0) w2q[k] = p;
    } else {
        int t = (b - NV - 128) * 256 + threadIdx.x;   // 0..4095
        if (t < NV) out[t] = bo2[t];
        if (t < 1152) zreg[t] = 0.f;                  // s[64] + hid[1024] + sync[64]
    }
}

// ---------------------------------------------------------------------------
// KB: g = spmm(adj, h); fused logits[r] = dot(g[r,:], w2q)  (unroll-2 gather)
__global__ void kB_spmm_g(const int* __restrict__ rcnt, const int* __restrict__ cols,
                          const float* __restrict__ vals, const float* __restrict__ h,
                          const float* __restrict__ w2q, float* __restrict__ g,
                          float* __restrict__ logits) {
    int r = blockIdx.x;
    __shared__ int cs[CAP];
    __shared__ float vsh[CAP];
    __shared__ float red[4];
    int cnt = rcnt[r];
    if (threadIdx.x < cnt) {
        cs[threadIdx.x] = cols[r * CAP + threadIdx.x] * NH;
        vsh[threadIdx.x] = vals[r * CAP + threadIdx.x];
    }
    __syncthreads();
    int c = threadIdx.x * 2;
    float2 acc = {0.f, 0.f};
    int j = 0;
    for (; j + 2 <= cnt; j += 2) {
        int c0 = cs[j], c1 = cs[j + 1];
        float v0 = vsh[j], v1 = vsh[j + 1];
        float2 wa = *(const float2*)(h + (size_t)c0 + c);
        float2 wb = *(const float2*)(h + (size_t)c1 + c);
        acc.x = fmaf(v0, wa.x, acc.x); acc.y = fmaf(v0, wa.y, acc.y);
        acc.x = fmaf(v1, wb.x, acc.x); acc.y = fmaf(v1, wb.y, acc.y);
    }
    if (j < cnt) {
        float2 wa = *(const float2*)(h + (size_t)cs[j] + c);
        acc.x = fmaf(vsh[j], wa.x, acc.x); acc.y = fmaf(vsh[j], wa.y, acc.y);
    }
    *(float2*)(g + (size_t)r * NH + c) = acc;
    float2 wq = *(const float2*)(w2q + c);
    float pp = acc.x * wq.x + acc.y * wq.y;
    for (int o = 32; o > 0; o >>= 1) pp += __shfl_down(pp, o);
    if ((threadIdx.x & 63) == 0) red[threadIdx.x >> 6] = pp;
    __syncthreads();
    if (threadIdx.x == 0) logits[r] = red[0] + red[1] + red[2] + red[3];
}

// ---------------------------------------------------------------------------
// KC: Ppart[vs] = mvmh_chunk @ g_chunk (lanes 0..49), Epart[vs] (lane 50).
//     R5 lesson: wave-uniform broadcast GLOBAL loads of g were latency-bound
//     (VGPR=16, MLP~1, 56us). Now g chunk is staged into LDS with coalesced
//     lane-parallel float4 loads; inner loop reads g via LDS b128 broadcast.
__global__ void kC_PE(const float* __restrict__ mvmh, const float* __restrict__ g,
                      const float* __restrict__ logits, float* __restrict__ Ppart,
                      float* __restrict__ Epart, float* __restrict__ s) {
    __shared__ float mvs[(NM + 1) * (VCH + 1)];
    __shared__ float g_lds[VCH][32];
    __shared__ float red[4];
    int cb = blockIdx.x & (CB - 1);
    int vs = blockIdx.x / CB;
    int v0 = vs * VCH;
    int C = cb * 32;
    int tid = threadIdx.x;

    // stage mv chunk (rows 0..49)
    for (int i = tid; i < NM * VCH; i += 256) {
        int m = i / VCH, vv = i - m * VCH;
        mvs[m * (VCH + 1) + vv] = mvmh[(size_t)m * NV + v0 + vv];
    }
    // stage g chunk [VCH][32] via lane-parallel float4 (high MLP, coalesced)
    for (int i = tid; i < VCH * 8; i += 256) {
        int vv = i >> 3, c4 = i & 7;
        float4 gv = *((const float4*)(g + (size_t)(v0 + vv) * NH + C) + c4);
        *((float4*)&g_lds[vv][c4 * 4]) = gv;
    }
    // block-redundant softmax scalars over logits[0..3999]
    float lmx = -1e30f;
    for (int i = tid; i < NV; i += 256) lmx = fmaxf(lmx, logits[i]);
    for (int o = 32; o > 0; o >>= 1) lmx = fmaxf(lmx, __shfl_xor(lmx, o));
    if ((tid & 63) == 0) red[tid >> 6] = lmx;
    __syncthreads();
    float mx = fmaxf(fmaxf(red[0], red[1]), fmaxf(red[2], red[3]));
    __syncthreads();
    float lsum = 0.f;
    for (int i = tid; i < NV; i += 256) lsum += __expf(logits[i] - mx);
    for (int o = 32; o > 0; o >>= 1) lsum += __shfl_xor(lsum, o);
    if ((tid & 63) == 0) red[tid >> 6] = lsum;
    __syncthreads();
    float inv = 1.f / (red[0] + red[1] + red[2] + red[3]);
    for (int i = tid; i < VCH; i += 256)
        mvs[NM * (VCH + 1) + i] = __expf(logits[v0 + i] - mx) * inv;
    __syncthreads();

    int w = tid >> 6, l = tid & 63;
    int Cw = w * 8;                      // this wave's 8-col slice within the 32
    int lc = (l <= NM) ? l : 0;
    const float* mrow = mvs + lc * (VCH + 1);
    float acc[8];
    float accs = 0.f;
#pragma unroll
    for (int i = 0; i < 8; ++i) acc[i] = 0.f;
    for (int vv = 0; vv < VCH; ++vv) {
        float t = mrow[vv];
        float4 ga = *((const float4*)&g_lds[vv][Cw]);
        float4 gb = *((const float4*)&g_lds[vv][Cw + 4]);
        acc[0] = fmaf(t, ga.x, acc[0]);
        acc[1] = fmaf(t, ga.y, acc[1]);
        acc[2] = fmaf(t, ga.z, acc[2]);
        acc[3] = fmaf(t, ga.w, acc[3]);
        acc[4] = fmaf(t, gb.x, acc[4]);
        acc[5] = fmaf(t, gb.y, acc[5]);
        acc[6] = fmaf(t, gb.z, acc[6]);
        acc[7] = fmaf(t, gb.w, acc[7]);
        accs += t;
    }
    if (l < NM) {
        float* dst = Ppart + ((size_t)vs * NM + l) * NH + C + Cw;
        float4 o0 = {acc[0], acc[1], acc[2], acc[3]};
        float4 o1 = {acc[4], acc[5], acc[6], acc[7]};
        *(float4*)dst = o0;
        *(float4*)(dst + 4) = o1;
    } else if (l == NM) {
        float* dst = Epart + (size_t)vs * NH + C + Cw;
        float4 e0 = {acc[0], acc[1], acc[2], acc[3]};
        float4 e1 = {acc[4], acc[5], acc[6], acc[7]};
        *(float4*)dst = e0;
        *(float4*)(dst + 4) = e1;
    }
    if (cb == 0 && w == 0 && l < NM) atomicAdd(&s[l], accs);
}

// ---------------------------------------------------------------------------
// KT: fused tail = {rowsW2+KQG} -> flag -> {hops/feat + gemv1} -> flag ->
//     {gemv2 on ALL 256 blocks}. Producers: one RELEASE fetch_add after
//     __syncthreads. Consumers: RELAXED spin + s_sleep, then one ACQUIRE.
//     256 blocks x 4 waves fit residency under any dispatch distribution.
__global__ __launch_bounds__(256) void kT_tail(
    const float* __restrict__ Ppart, const float* __restrict__ Epart,
    const float* __restrict__ W2, const float* __restrict__ b2,
    const float* __restrict__ s, const float* __restrict__ query,
    const float* __restrict__ keys, const float* __restrict__ Wo1,
    const float* __restrict__ bo1, const float* __restrict__ Wo2,
    float* __restrict__ R, float* __restrict__ ctxE, float* __restrict__ G,
    float* __restrict__ KQ, float* __restrict__ hid, float* __restrict__ out,
    int* __restrict__ sync) {
    int bid = blockIdx.x, tid = threadIdx.x;
    __shared__ float xs[NH];
    __shared__ float ys[NH];
    __shared__ float Gs[NM * NM];
    __shared__ float aws[NM];
    __shared__ float As[NM];
    __shared__ float fs[64];
    __shared__ float rh[64];

    // ---------------- phase 1: reduce partials; R/ctxE = row @ W2; G/KQ ----
    if (bid < NP1) {
        int m = bid;
        if (m < NM) {
            for (int k = tid; k < NH; k += 256) {
                float v = 0.f;
                const float* p = Ppart + (size_t)m * NH + k;
                for (int q = 0; q < VS; ++q) v += p[(size_t)q * NM * NH];
                xs[k] = v;
            }
        } else {
            for (int k = tid; k < NH; k += 256) {
                float v = 0.f;
                for (int q = 0; q < VS; ++q) v += Epart[(size_t)q * NH + k];
                xs[k] = v;
            }
        }
        __syncthreads();
        int c = tid * 2;
        float2 acc = {0.f, 0.f};
        const float4* xs4 = (const float4*)xs;
        for (int kk = 0; kk < NH / 4; ++kk) {
            float4 x = xs4[kk];
            int k = kk * 4;
            float2 w0 = *(const float2*)(W2 + (size_t)k * NH + c);
            float2 w1 = *(const float2*)(W2 + (size_t)(k + 1) * NH + c);
            float2 w2v = *(const float2*)(W2 + (size_t)(k + 2) * NH + c);
            float2 w3 = *(const float2*)(W2 + (size_t)(k + 3) * NH + c);
            acc.x = fmaf(x.x, w0.x, acc.x);  acc.y = fmaf(x.x, w0.y, acc.y);
            acc.x = fmaf(x.y, w1.x, acc.x);  acc.y = fmaf(x.y, w1.y, acc.y);
            acc.x = fmaf(x.z, w2v.x, acc.x); acc.y = fmaf(x.z, w2v.y, acc.y);
            acc.x = fmaf(x.w, w3.x, acc.x);  acc.y = fmaf(x.w, w3.y, acc.y);
        }
        float2 bb = *(const float2*)(b2 + c);
        if (m < NM) {
            float sm = s[m];
            acc.x += sm * bb.x;
            acc.y += sm * bb.y;
            *(float2*)(R + (size_t)m * NH + c) = acc;
            ys[c] = acc.x; ys[c + 1] = acc.y;
        } else {
            acc.x += bb.x;
            acc.y += bb.y;
            *(float2*)(ctxE + c) = acc;
            float2 q2 = *(const float2*)(query + c);
            ys[c] = q2.x; ys[c + 1] = q2.y;
        }
        __syncthreads();
        int wid = tid >> 6, lane = tid & 63;
        for (int mm = wid; mm < NM; mm += 4) {
            const float* kr = keys + (size_t)mm * NH;
            float p = 0.f;
            for (int jj = lane; jj < NH; jj += 64) p = fmaf(kr[jj], ys[jj], p);
            for (int o = 32; o > 0; o >>= 1) p += __shfl_down(p, o);
            if (lane == 0) {
                if (m < NM) G[m * NM + mm] = p;
                else KQ[mm] = p;
            }
        }
        __syncthreads();   // drain all stores before the release-add
        if (tid == 0)
            __hip_atomic_fetch_add(&sync[0], 1, __ATOMIC_RELEASE, __HIP_MEMORY_SCOPE_AGENT);
    }

    // ---------------- phase 2: hops/feat + hid += fs @ Wo1 ----------------
    if (bid < NP2) {
        if (tid == 0) {
            while (__hip_atomic_load(&sync[0], __ATOMIC_RELAXED, __HIP_MEMORY_SCOPE_AGENT) < NP1)
                __builtin_amdgcn_s_sleep(2);
            (void)__hip_atomic_load(&sync[0], __ATOMIC_ACQUIRE, __HIP_MEMORY_SCOPE_AGENT);
        }
        __syncthreads();
        int ks = bid >> 2, jt = bid & 3;
        int k0 = ks * 64;
        int seg = k0 >> 9;   // 0: query, 1: context_o, 2: ctxE
        if (seg == 1) {
            for (int i = tid; i < NM * NM; i += 256) Gs[i] = G[i];
            __syncthreads();
            if (tid < 64) {
                int l = tid;
                float L = (l < NM) ? KQ[l] : -1e30f;
                float Aacc = 0.f;
                for (int t = 0; t < NHOPS; ++t) {
                    float mxv = L;
                    for (int o = 32; o > 0; o >>= 1) mxv = fmaxf(mxv, __shfl_xor(mxv, o));
                    float e = (l < NM) ? __expf(L - mxv) : 0.f;
                    float sm = e;
                    for (int o = 32; o > 0; o >>= 1) sm += __shfl_xor(sm, o);
                    float aw = e / sm;
                    Aacc += aw;
                    if (l < NM) aws[l] = aw;       // intra-wave LDS, hw-ordered
                    if (l < NM) {
                        float d = 0.f;
                        for (int mp = 0; mp < NM; ++mp) d = fmaf(aws[mp], Gs[mp * NM + l], d);
                        L += d;
                    }
                }
                if (l < NM) As[l] = Aacc;
            }
            __syncthreads();
            if (tid < 64) {
                int kk = k0 + tid - NH;            // 0..511
                float v = query[kk];
                for (int mp = 0; mp < NM; ++mp) v = fmaf(As[mp], R[mp * NH + kk], v);
                fs[tid] = fmaxf(v, 0.f);
            }
        } else if (seg == 0) {
            if (tid < 64) fs[tid] = fmaxf(query[k0 + tid], 0.f);
        } else {
            if (tid < 64) fs[tid] = fmaxf(ctxE[k0 + tid - 2 * NH], 0.f);
        }
        __syncthreads();
        int j = jt * 256 + tid;
        float acc = 0.f;
        const float4* fs4 = (const float4*)fs;
#pragma unroll
        for (int ii = 0; ii < 16; ++ii) {
            float4 f = fs4[ii];
            int k = k0 + ii * 4;
            acc = fmaf(f.x, Wo1[(size_t)k * 1024 + j], acc);
            acc = fmaf(f.y, Wo1[(size_t)(k + 1) * 1024 + j], acc);
            acc = fmaf(f.z, Wo1[(size_t)(k + 2) * 1024 + j], acc);
            acc = fmaf(f.w, Wo1[(size_t)(k + 3) * 1024 + j], acc);
        }
        atomicAdd(&hid[j], acc);                  // device-scope, lands coherent
        __syncthreads();                          // drain atomics before release
        if (tid == 0)
            __hip_atomic_fetch_add(&sync[1], 1, __ATOMIC_RELEASE, __HIP_MEMORY_SCOPE_AGENT);
    }

    // ---------------- phase 3: out += relu(hid + bo1) @ Wo2 ----------------
    if (tid == 0) {
        while (__hip_atomic_load(&sync[1], __ATOMIC_RELAXED, __HIP_MEMORY_SCOPE_AGENT) < NP2)
            __builtin_amdgcn_s_sleep(2);
        (void)__hip_atomic_load(&sync[1], __ATOMIC_ACQUIRE, __HIP_MEMORY_SCOPE_AGENT);
    }
    __syncthreads();
    {
        int ks2 = bid >> 4;        // 0..15, k-split of 64
        int vt = bid & 15;         // 0..15, 256-col strip
        int k0 = ks2 * 64;
        if (tid < 64) rh[tid] = fmaxf(hid[k0 + tid] + bo1[k0 + tid], 0.f);
        __syncthreads();
        int v = vt * 256 + tid;
        if (v < NV) {
            float acc = 0.f;
            const float4* rh4 = (const float4*)rh;
#pragma unroll
            for (int ii = 0; ii < 16; ++ii) {
                float4 f = rh4[ii];
                int k = k0 + ii * 4;
                acc = fmaf(f.x, Wo2[(size_t)k * NV + v], acc);
                acc = fmaf(f.y, Wo2[(size_t)(k + 1) * NV + v], acc);
                acc = fmaf(f.z, Wo2[(size_t)(k + 2) * NV + v], acc);
                acc = fmaf(f.w, Wo2[(size_t)(k + 3) * NV + v], acc);
            }
            atomicAdd(&out[v], acc);
        }
    }
}

// ---------------------------------------------------------------------------
extern "C" void kernel_launch(void* const* d_in, const int* in_sizes, int n_in,
                              void* d_out, int out_size, void* d_ws, size_t ws_size,
                              hipStream_t stream) {
    const float* query = (const float*)d_in[0];
    const float* keys  = (const float*)d_in[1];
    const float* mvmh  = (const float*)d_in[2];
    const float* adj   = (const float*)d_in[3];
    const float* W1    = (const float*)d_in[4];
    const float* b1    = (const float*)d_in[5];
    const float* W2    = (const float*)d_in[6];
    const float* b2    = (const float*)d_in[7];
    const float* Wo1   = (const float*)d_in[8];
    const float* bo1   = (const float*)d_in[9];
    const float* Wo2   = (const float*)d_in[10];
    const float* bo2   = (const float*)d_in[11];
    float* out = (float*)d_out;

    char* w = (char*)d_ws;
    int* rcnt = (int*)w;        w += 4096 * 4;
    int* cols = (int*)w;        w += NV * CAP * 4;
    float* vals = (float*)w;    w += NV * CAP * 4;
    float* h = (float*)w;       w += (size_t)NV * NH * 4;
    float* g = (float*)w;       w += (size_t)NV * NH * 4;
    float* logits = (float*)w;  w += 4096 * 4;
    float* w2q = (float*)w;     w += NH * 4;
    float* Ppart = (float*)w;   w += (size_t)VS * NM * NH * 4;   // 640000 floats
    float* Epart = (float*)w;   w += VS * NH * 4;                // 12800 floats
    float* zreg = (float*)w;                                     // s+hid+sync (1152 floats)
    float* s = (float*)w;       w += 64 * 4;
    float* hid = (float*)w;     w += 1024 * 4;
    int* syncc = (int*)w;       w += 64 * 4;
    float* R = (float*)w;       w += NM * NH * 4;
    float* ctxE = (float*)w;    w += NH * 4;
    float* G = (float*)w;       w += 2560 * 4;
    float* KQ = (float*)w;      w += 64 * 4;

    kA_csr_h<<<NV + 128 + 16, 256, 0, stream>>>(adj, query, W1, b1, W2, bo2,
                                                rcnt, cols, vals, h, w2q, zreg, out);
    kB_spmm_g<<<NV, 256, 0, stream>>>(rcnt, cols, vals, h, w2q, g, logits);
    kC_PE<<<CB * VS, 256, 0, stream>>>(mvmh, g, logits, Ppart, Epart, s);
    kT_tail<<<TGRID, 256, 0, stream>>>(Ppart, Epart, W2, b2, s, query, keys,
                                       Wo1, bo1, Wo2, R, ctxE, G, KQ, hid, out, syncc);
}